// Round 4
// baseline (129.821 us; speedup 1.0000x reference)
//
#include <hip/hip_runtime.h>
#include <hip/hip_bf16.h>

#define BB 256
#define LL 512
#define NIDS 2000

typedef float nfloat4 __attribute__((ext_vector_type(4)));

// workspace: table only (513*64 floats)
#define WS_TABLE 0

// ---------------------------------------------------------------------------
// Table: T(c)[g] = sum_f relu(c*w1[f]+b1[f]) * w2[f][g] + b2[g], c in [0,512]
// ---------------------------------------------------------------------------
__global__ __launch_bounds__(64) void k_table(
    const float* __restrict__ w1, const float* __restrict__ b1,
    const float* __restrict__ w2, const float* __restrict__ b2,
    float* __restrict__ table) {
  int c = blockIdx.x, f = threadIdx.x;
  __shared__ float h[64];
  h[f] = fmaxf((float)c * w1[f] + b1[f], 0.f);
  __syncthreads();
  float acc = b2[f];
#pragma unroll
  for (int g = 0; g < 64; ++g) acc += h[g] * w2[g * 64 + f];
  table[c * 64 + f] = acc;
}

// ---------------------------------------------------------------------------
// Fused per-(batch,dir) kernel: histogram + pair dedup + linear cross-attn
// + LN + scatter. LDS regions are reused across phases (~49 KB static).
// Register discipline: at most ONE 64-float array (wa) live at any time.
// ---------------------------------------------------------------------------
__global__ __launch_bounds__(256, 3) void k_fused(
    const int* __restrict__ src, const int* __restrict__ dst,
    const float* __restrict__ table,
    const float* __restrict__ Wq, const float* __restrict__ Wk,
    const float* __restrict__ Wv, const float* __restrict__ Wo,
    const float* __restrict__ bo, const float* __restrict__ lng,
    const float* __restrict__ lnb, float* __restrict__ out) {
  // ---- LDS layout (byte offsets; regions reused across phases) ----
  // [0, 16384)      hist (4000 ints) -> Phase A pool (3072 f) -> Wo stage /
  //                 Phase B row-out chunk (4096 f)
  // [16384, 20480)  hash keys (1024)  -> hidx in-place after compaction
  // [20480, 24576)  hash mult (1024)  -> featb(256f) qbuf(256f) sred(256f)
  // [24576, 41984)  Mg: MT then GT2, 64 x stride-68 floats
  // [41984, 50176)  xkey / ckey / cmult / pidxl (512 ints each)
  // [50176]         np
  __shared__ __align__(16) char smem[50192];
  int*   hist  = (int*)smem;
  float* poolF = (float*)smem;
  int*   hkey  = (int*)(smem + 16384);
  int*   hmult = (int*)(smem + 20480);
  float* fbF   = (float*)(smem + 20480);   // featb 0..255 | qbuf 256..511 | sred 512..767
  float* Mg    = (float*)(smem + 24576);   // stride 68
  int*   xkey  = (int*)(smem + 41984);
  int*   ckey  = (int*)(smem + 44032);
  int*   cmult = (int*)(smem + 46080);
  int*   pidxl = (int*)(smem + 48128);
  int*   npp   = (int*)(smem + 50176);

  int bd = blockIdx.x, b = bd >> 1, dir = bd & 1;
  int tid = threadIdx.x, tx = tid & 63, ty = tid >> 6;
  int e0 = ty * 16;

  // ---- histograms (both sides) ----
  const int* s = src + b * LL;
  const int* d = dst + b * LL;
  int sid0 = s[tid], sid1 = s[tid + 256];
  int did0 = d[tid], did1 = d[tid + 256];
  for (int i = tid; i < 4000; i += 256) hist[i] = 0;
  __syncthreads();
  atomicAdd(&hist[sid0], 1);        atomicAdd(&hist[sid1], 1);
  atomicAdd(&hist[2000 + did0], 1); atomicAdd(&hist[2000 + did1], 1);
  __syncthreads();

  int x0 = dir ? did0 : sid0, x1 = dir ? did1 : sid1;
  int c0 = dir ? sid0 : did0, c1 = dir ? sid1 : did1;
  const int* hx = dir ? hist + 2000 : hist;   // own-side counts for x ids
  const int* hc = dir ? hist : hist + 2000;   // own-side counts for c ids

  // ---- c-side dedup: keys + multiplicity ----
  for (int i = tid; i < 1024; i += 256) { hkey[i] = -1; hmult[i] = 0; }
  if (tid == 0) *npp = 0;
  __syncthreads();
  for (int r = 0; r < 2; ++r) {
    int id = r ? c1 : c0;
    int ca = 0, cb = 0;
    if (id != 0) { ca = hc[id]; cb = hx[id]; }
    int key = ca | (cb << 10);
    int h = (int)(((unsigned)key * 2654435761u) >> 22) & 1023;
    while (true) {
      int old = atomicCAS(&hkey[h], -1, key);
      if (old == -1 || old == key) break;
      h = (h + 1) & 1023;
    }
    atomicAdd(&hmult[h], 1);
  }
  __syncthreads();
  for (int i = tid; i < 1024; i += 256) {
    if (hkey[i] != -1) {
      int idx = atomicAdd(npp, 1);
      ckey[idx]  = hkey[i];
      cmult[idx] = hmult[i];
    }
  }
  __syncthreads();
  int Pc = *npp;
  __syncthreads();

  // ---- x-side dedup: keys + per-row pair index ----
  for (int i = tid; i < 1024; i += 256) { hkey[i] = -1; hmult[i] = 0; }
  if (tid == 0) *npp = 0;
  __syncthreads();
  int slot0, slot1;
  for (int r = 0; r < 2; ++r) {
    int id = r ? x1 : x0;
    int ca = 0, cb = 0;
    if (id != 0) { ca = hx[id]; cb = hc[id]; }
    int key = ca | (cb << 10);
    int h = (int)(((unsigned)key * 2654435761u) >> 22) & 1023;
    while (true) {
      int old = atomicCAS(&hkey[h], -1, key);
      if (old == -1 || old == key) break;
      h = (h + 1) & 1023;
    }
    if (r) slot1 = h; else slot0 = h;
  }
  __syncthreads();
  for (int i = tid; i < 1024; i += 256) {
    int k = hkey[i];
    if (k != -1) {
      int idx = atomicAdd(npp, 1);
      xkey[idx] = k;
      hkey[i] = idx;   // overwrite key with compacted index
    }
  }
  __syncthreads();
  pidxl[tid]       = hkey[slot0];
  pidxl[tid + 256] = hkey[slot1];
  int Px = *npp;
  __syncthreads();   // hist region now dead -> becomes Phase A pool

  // ---- Phase A: M[d][e] = sum_j n_j exp(k_j[d]) v_j[e] / colsum ----
  float* featA = poolF;            // 16 rows x 64
  float* pA    = poolF + 1024;
  float* vA    = poolF + 2048;
  float wa[64];
  float macc[16];
#pragma unroll
  for (int e = 0; e < 16; ++e) macc[e] = 0.f;
  float sacc = 0.f;

  for (int j0 = 0; j0 < Pc; j0 += 16) {
    int cN = min(16, Pc - j0);
    // pass 1: feat + p (wa = Wk column tx)
#pragma unroll
    for (int f = 0; f < 64; ++f) wa[f] = Wk[f * 64 + tx];
    for (int j = ty; j < cN; j += 4) {
      int key = ckey[j0 + j];
      int ca = key & 1023, cb = key >> 10;
      featA[j * 64 + tx] = table[ca * 64 + tx] + table[cb * 64 + tx];
      float kr = 0.f;
      const float4* fb4 = (const float4*)&featA[j * 64];
#pragma unroll
      for (int q = 0; q < 16; ++q) {
        float4 fv = fb4[q];
        kr += fv.x * wa[4 * q] + fv.y * wa[4 * q + 1] + fv.z * wa[4 * q + 2] + fv.w * wa[4 * q + 3];
      }
      float p = __expf(kr) * (float)cmult[j0 + j];  // |kr| ~ O(10): safe fp32
      sacc += p;
      pA[j * 64 + tx] = p;
    }
    // pass 2: v (wa = Wv column tx; feat rows are wave-local)
#pragma unroll
    for (int f = 0; f < 64; ++f) wa[f] = Wv[f * 64 + tx];
    for (int j = ty; j < cN; j += 4) {
      float vr = 0.f;
      const float4* fb4 = (const float4*)&featA[j * 64];
#pragma unroll
      for (int q = 0; q < 16; ++q) {
        float4 fv = fb4[q];
        vr += fv.x * wa[4 * q] + fv.y * wa[4 * q + 1] + fv.z * wa[4 * q + 2] + fv.w * wa[4 * q + 3];
      }
      vA[j * 64 + tx] = vr;
    }
    __syncthreads();
    // M accumulation: thread (tx,ty) owns M[d=tx][e0..e0+15]
    for (int jj = 0; jj < cN; ++jj) {
      float pg = pA[jj * 64 + tx];
      const float4* vb4 = (const float4*)&vA[jj * 64 + e0];
#pragma unroll
      for (int q = 0; q < 4; ++q) {
        float4 vv = vb4[q];
        macc[4 * q]     += pg * vv.x; macc[4 * q + 1] += pg * vv.y;
        macc[4 * q + 2] += pg * vv.z; macc[4 * q + 3] += pg * vv.w;
      }
    }
    __syncthreads();
  }
  fbF[512 + ty * 64 + tx] = sacc;
  __syncthreads();
  float inv = 1.f / (fbF[512 + tx] + fbF[576 + tx] + fbF[640 + tx] + fbF[704 + tx]);
  // MT[f][d] = M[d][f] (lane-consecutive writes)
#pragma unroll
  for (int e = 0; e < 16; ++e) Mg[(e0 + e) * 68 + tx] = macc[e] * inv;
  for (int i = tid; i < 4096; i += 256) poolF[i] = Wo[i];  // stage Wo
  // prefetch Wq column + epilogue scalars (wa free until Phase B)
#pragma unroll
  for (int f = 0; f < 64; ++f) wa[f] = Wq[f * 64 + tx];
  float bov = bo[tx], lg = lng[tx], lb = lnb[tx];
  __syncthreads();

  // ---- G = M @ Wo: thread owns G[d=tx][o=e0..e0+15] ----
#pragma unroll
  for (int e = 0; e < 16; ++e) macc[e] = 0.f;
  for (int f = 0; f < 64; ++f) {
    float mt = Mg[f * 68 + tx];                 // lane-consecutive, conflict-free
    const float4* wo4 = (const float4*)&poolF[f * 64 + e0];  // wave-broadcast
#pragma unroll
    for (int q = 0; q < 4; ++q) {
      float4 w4 = wo4[q];
      macc[4 * q]     += mt * w4.x; macc[4 * q + 1] += mt * w4.y;
      macc[4 * q + 2] += mt * w4.z; macc[4 * q + 3] += mt * w4.w;
    }
  }
  __syncthreads();   // all MT reads done
  // GT2[o][d] = G[d][o]  (row o contiguous in d -> float4 reads in Phase B)
#pragma unroll
  for (int e = 0; e < 16; ++e) Mg[(e0 + e) * 68 + tx] = macc[e];
  __syncthreads();

  // ---- Phase B: per distinct x pair -> output row; chunked scatter ----
  for (int i0 = 0; i0 < Px; i0 += 64) {
    int cN = min(64, Px - i0);
    for (int jj = ty; jj < cN; jj += 4) {
      int key = xkey[i0 + jj];
      int ca = key & 1023, cb = key >> 10;
      float fv = table[ca * 64 + tx] + table[cb * 64 + tx];
      fbF[ty * 64 + tx] = fv;
      float qr = 0.f;
      const float4* fb4 = (const float4*)&fbF[ty * 64];
#pragma unroll
      for (int q = 0; q < 16; ++q) {
        float4 f4v = fb4[q];
        qr += f4v.x * wa[4 * q] + f4v.y * wa[4 * q + 1] + f4v.z * wa[4 * q + 2] + f4v.w * wa[4 * q + 3];
      }
      float p = __expf(qr);
      float sum = p;
#pragma unroll
      for (int off = 32; off >= 1; off >>= 1) sum += __shfl_xor(sum, off, 64);
      float qh = p / sum * 0.125f;   // softmax * F^-0.5
      fbF[256 + ty * 64 + tx] = qh;
      float at = 0.f;
      const float4* qb4 = (const float4*)&fbF[256 + ty * 64];
      const float4* gt4 = (const float4*)&Mg[tx * 68];
#pragma unroll
      for (int q = 0; q < 16; ++q) {
        float4 qv = qb4[q];
        float4 gv = gt4[q];
        at += qv.x * gv.x + qv.y * gv.y + qv.z * gv.z + qv.w * gv.w;
      }
      float r = fv + at + bov;
      float mu = r;
#pragma unroll
      for (int off = 32; off >= 1; off >>= 1) mu += __shfl_xor(mu, off, 64);
      mu *= (1.f / 64.f);
      float dv = r - mu;
      float var = dv * dv;
#pragma unroll
      for (int off = 32; off >= 1; off >>= 1) var += __shfl_xor(var, off, 64);
      var *= (1.f / 64.f);
      poolF[jj * 64 + tx] = dv * rsqrtf(var + 1e-5f) * lg + lb;
    }
    __syncthreads();
    const nfloat4* w4 = (const nfloat4*)poolF;
    nfloat4* out4 = (nfloat4*)(out + (size_t)(dir * BB + b) * (LL * 64));
    for (int idx = tid; idx < 512 * 16; idx += 256) {
      int l = idx >> 4, q = idx & 15;
      int pid = pidxl[l];
      if (pid >= i0 && pid < i0 + cN)
        __builtin_nontemporal_store(w4[(pid - i0) * 16 + q], &out4[l * 16 + q]);
    }
    __syncthreads();
  }
}

extern "C" void kernel_launch(void* const* d_in, const int* in_sizes, int n_in,
                              void* d_out, int out_size, void* d_ws, size_t ws_size,
                              hipStream_t stream) {
  const int* src  = (const int*)d_in[0];
  const int* dst  = (const int*)d_in[1];
  const float* w1 = (const float*)d_in[2];
  const float* b1 = (const float*)d_in[3];
  const float* w2 = (const float*)d_in[4];
  const float* b2 = (const float*)d_in[5];
  const float* Wq = (const float*)d_in[6];
  const float* Wk = (const float*)d_in[7];
  const float* Wv = (const float*)d_in[8];
  const float* Wo = (const float*)d_in[9];
  const float* bo = (const float*)d_in[10];
  const float* lng = (const float*)d_in[11];
  const float* lnb = (const float*)d_in[12];
  float* out = (float*)d_out;
  float* table = (float*)d_ws + WS_TABLE;

  k_table<<<dim3(513), dim3(64), 0, stream>>>(w1, b1, w2, b2, table);
  k_fused<<<dim3(512), dim3(256), 0, stream>>>(src, dst, table,
                                               Wq, Wk, Wv, Wo, bo, lng, lnb, out);
}

// Round 5
// 120.728 us; speedup vs baseline: 1.0753x; 1.0753x over previous
//
#include <hip/hip_runtime.h>
#include <hip/hip_bf16.h>

#define BB 256
#define LL 512

typedef float nfloat4 __attribute__((ext_vector_type(4)));

// ---------------------------------------------------------------------------
// Single fused kernel per (batch, dir):
//   histograms -> pair dedup -> per-block encode table (distinct counts only,
//   in LDS) -> linear cross-attn (deduped) -> LN -> scatter to 512 positions.
// Register discipline: ONE 64-float array (wa: w2col -> Wk -> Wv -> Wq).
// LDS ~78 KB -> 2 blocks/CU; grid 512 = fully co-resident.
// ---------------------------------------------------------------------------
__global__ __launch_bounds__(256, 2) void k_all(
    const int* __restrict__ src, const int* __restrict__ dst,
    const float* __restrict__ w1, const float* __restrict__ b1,
    const float* __restrict__ w2, const float* __restrict__ b2,
    const float* __restrict__ Wq, const float* __restrict__ Wk,
    const float* __restrict__ Wv, const float* __restrict__ Wo,
    const float* __restrict__ bo, const float* __restrict__ lng,
    const float* __restrict__ lnb, float* __restrict__ out) {
  // ---- LDS layout (byte offsets; regions reused across phases) ----
  // [0,16384)       A: hist(4000 int) -> h-rows + Phase A pool -> Wo stage ->
  //                    Phase B row-out chunk
  // [16384,49152)   T: hash hkey/hmult (8 KB, dedup only) -> tableL 128x64 f
  // [49152,66560)   Mg: cflag/clist (prep) -> MT then GT2 (64 x stride-68 f)
  // [66560,74752)   K: xkey | ckey | cmult | pidxl (512 ints each)
  // [74752,77824)   F: featb | qbuf | sred (256 f each)
  // [77824]         npp
  __shared__ __align__(16) char smem[77840];
  int*   hist  = (int*)smem;
  float* poolF = (float*)smem;
  int*   hkey  = (int*)(smem + 16384);
  int*   hmult = (int*)(smem + 20480);
  float* tabL  = (float*)(smem + 16384);   // 128 rows x 64
  int*   cflag = (int*)(smem + 49152);     // 513 ints (then cmap)
  int*   clist = (int*)(smem + 51252);     // 128 ints
  float* Mg    = (float*)(smem + 49152);   // stride 68 (after prep)
  int*   xkey  = (int*)(smem + 66560);
  int*   ckey  = (int*)(smem + 68608);
  int*   cmult = (int*)(smem + 70656);
  int*   pidxl = (int*)(smem + 72704);
  float* fbF   = (float*)(smem + 74752);   // featb 0..255 | qbuf 256..511 | sred 512..767
  int*   npp   = (int*)(smem + 77824);

  int bd = blockIdx.x, b = bd >> 1, dir = bd & 1;
  int tid = threadIdx.x, tx = tid & 63, ty = tid >> 6;
  int e0 = ty * 16;

  // ---- histograms (both sides) ----
  const int* s = src + b * LL;
  const int* d = dst + b * LL;
  int sid0 = s[tid], sid1 = s[tid + 256];
  int did0 = d[tid], did1 = d[tid + 256];
  for (int i = tid; i < 4000; i += 256) hist[i] = 0;
  __syncthreads();
  atomicAdd(&hist[sid0], 1);        atomicAdd(&hist[sid1], 1);
  atomicAdd(&hist[2000 + did0], 1); atomicAdd(&hist[2000 + did1], 1);
  __syncthreads();

  int x0 = dir ? did0 : sid0, x1 = dir ? did1 : sid1;
  int c0 = dir ? sid0 : did0, c1 = dir ? sid1 : did1;
  const int* hx = dir ? hist + 2000 : hist;
  const int* hc = dir ? hist : hist + 2000;

  // ---- c-side dedup: keys + multiplicity ----
  for (int i = tid; i < 1024; i += 256) { hkey[i] = -1; hmult[i] = 0; }
  if (tid == 0) *npp = 0;
  __syncthreads();
  for (int r = 0; r < 2; ++r) {
    int id = r ? c1 : c0;
    int ca = 0, cb = 0;
    if (id != 0) { ca = hc[id]; cb = hx[id]; }
    int key = ca | (cb << 10);
    int h = (int)(((unsigned)key * 2654435761u) >> 22) & 1023;
    while (true) {
      int old = atomicCAS(&hkey[h], -1, key);
      if (old == -1 || old == key) break;
      h = (h + 1) & 1023;
    }
    atomicAdd(&hmult[h], 1);
  }
  __syncthreads();
  for (int i = tid; i < 1024; i += 256) {
    if (hkey[i] != -1) {
      int idx = atomicAdd(npp, 1);
      ckey[idx]  = hkey[i];
      cmult[idx] = hmult[i];
    }
  }
  __syncthreads();
  int Pc = *npp;
  __syncthreads();

  // ---- x-side dedup: keys + per-row pair index ----
  for (int i = tid; i < 1024; i += 256) { hkey[i] = -1; }
  if (tid == 0) *npp = 0;
  __syncthreads();
  int slot0, slot1;
  for (int r = 0; r < 2; ++r) {
    int id = r ? x1 : x0;
    int ca = 0, cb = 0;
    if (id != 0) { ca = hx[id]; cb = hc[id]; }
    int key = ca | (cb << 10);
    int h = (int)(((unsigned)key * 2654435761u) >> 22) & 1023;
    while (true) {
      int old = atomicCAS(&hkey[h], -1, key);
      if (old == -1 || old == key) break;
      h = (h + 1) & 1023;
    }
    if (r) slot1 = h; else slot0 = h;
  }
  __syncthreads();
  for (int i = tid; i < 1024; i += 256) {
    int k = hkey[i];
    if (k != -1) {
      int idx = atomicAdd(npp, 1);
      xkey[idx] = k;
      hkey[i] = idx;   // key -> compacted index
    }
  }
  __syncthreads();
  pidxl[tid]       = hkey[slot0];
  pidxl[tid + 256] = hkey[slot1];
  int Px = *npp;
  __syncthreads();

  // ---- collect distinct count values over all key components ----
  for (int i = tid; i < 513; i += 256) cflag[i] = 0;
  if (tid == 0) *npp = 0;
  __syncthreads();
  if (tid < Pc) { int k = ckey[tid]; cflag[k & 1023] = 1; cflag[k >> 10] = 1; }
  if (tid < Px) { int k = xkey[tid]; cflag[k & 1023] = 1; cflag[k >> 10] = 1; }
  __syncthreads();
  for (int c = tid; c < 513; c += 256) {
    if (cflag[c]) {
      int idx = atomicAdd(npp, 1);
      clist[idx] = c;
      cflag[c] = idx;   // cflag becomes cmap
    }
  }
  __syncthreads();
  int nc = *npp;        // provably <= 125
  // rewrite keys to table indices
  if (tid < Pc) { int k = ckey[tid]; ckey[tid] = cflag[k & 1023] | (cflag[k >> 10] << 10); }
  if (tid < Px) { int k = xkey[tid]; xkey[tid] = cflag[k & 1023] | (cflag[k >> 10] << 10); }
  __syncthreads();      // hash region dead -> tableL; hist dead -> pool

  // ---- build per-block encode table rows in LDS ----
  // T(c)[g] = b2[g] + sum_f relu(c*w1[f]+b1[f]) * w2[f][g]
  float wa[64];
#pragma unroll
  for (int f = 0; f < 64; ++f) wa[f] = w2[f * 64 + tx];   // w2 column tx
  {
    float w1v = w1[tx], b1v = b1[tx], b2v = b2[tx];
    for (int i = ty; i < nc; i += 4) {
      float c = (float)clist[i];
      poolF[ty * 64 + tx] = fmaxf(c * w1v + b1v, 0.f);    // wave-local h row
      float acc = b2v;
      const float4* h4 = (const float4*)&poolF[ty * 64];
#pragma unroll
      for (int q = 0; q < 16; ++q) {
        float4 hv = h4[q];
        acc += hv.x * wa[4 * q] + hv.y * wa[4 * q + 1] + hv.z * wa[4 * q + 2] + hv.w * wa[4 * q + 3];
      }
      tabL[i * 64 + tx] = acc;
    }
  }
  __syncthreads();

  // ---- Phase A: M[d][e] = sum_j n_j exp(k_j[d]) v_j[e] / colsum ----
  float* featA = poolF;            // 16 rows x 64
  float* pA    = poolF + 1024;
  float* vA    = poolF + 2048;
  float macc[16];
#pragma unroll
  for (int e = 0; e < 16; ++e) macc[e] = 0.f;
  float sacc = 0.f;

  for (int j0 = 0; j0 < Pc; j0 += 16) {
    int cN = min(16, Pc - j0);
#pragma unroll
    for (int f = 0; f < 64; ++f) wa[f] = Wk[f * 64 + tx];
    for (int j = ty; j < cN; j += 4) {
      int key = ckey[j0 + j];
      int ia = key & 1023, ib = key >> 10;
      featA[j * 64 + tx] = tabL[ia * 64 + tx] + tabL[ib * 64 + tx];
      float kr = 0.f;
      const float4* fb4 = (const float4*)&featA[j * 64];
#pragma unroll
      for (int q = 0; q < 16; ++q) {
        float4 fv = fb4[q];
        kr += fv.x * wa[4 * q] + fv.y * wa[4 * q + 1] + fv.z * wa[4 * q + 2] + fv.w * wa[4 * q + 3];
      }
      float p = __expf(kr) * (float)cmult[j0 + j];  // |kr| ~ O(10): safe fp32
      sacc += p;
      pA[j * 64 + tx] = p;
    }
#pragma unroll
    for (int f = 0; f < 64; ++f) wa[f] = Wv[f * 64 + tx];
    for (int j = ty; j < cN; j += 4) {
      float vr = 0.f;
      const float4* fb4 = (const float4*)&featA[j * 64];
#pragma unroll
      for (int q = 0; q < 16; ++q) {
        float4 fv = fb4[q];
        vr += fv.x * wa[4 * q] + fv.y * wa[4 * q + 1] + fv.z * wa[4 * q + 2] + fv.w * wa[4 * q + 3];
      }
      vA[j * 64 + tx] = vr;
    }
    __syncthreads();
    for (int jj = 0; jj < cN; ++jj) {
      float pg = pA[jj * 64 + tx];
      const float4* vb4 = (const float4*)&vA[jj * 64 + e0];
#pragma unroll
      for (int q = 0; q < 4; ++q) {
        float4 vv = vb4[q];
        macc[4 * q]     += pg * vv.x; macc[4 * q + 1] += pg * vv.y;
        macc[4 * q + 2] += pg * vv.z; macc[4 * q + 3] += pg * vv.w;
      }
    }
    __syncthreads();
  }
  fbF[512 + ty * 64 + tx] = sacc;
  __syncthreads();
  float inv = 1.f / (fbF[512 + tx] + fbF[576 + tx] + fbF[640 + tx] + fbF[704 + tx]);
  // MT[f][d] = M[d][f]
#pragma unroll
  for (int e = 0; e < 16; ++e) Mg[(e0 + e) * 68 + tx] = macc[e] * inv;
  for (int i = tid; i < 4096; i += 256) poolF[i] = Wo[i];  // stage Wo
#pragma unroll
  for (int f = 0; f < 64; ++f) wa[f] = Wq[f * 64 + tx];    // prefetch Wq col
  float bov = bo[tx], lg = lng[tx], lb = lnb[tx];
  __syncthreads();

  // ---- G = M @ Wo: thread owns G[d=tx][o=e0..e0+15] ----
#pragma unroll
  for (int e = 0; e < 16; ++e) macc[e] = 0.f;
  for (int f = 0; f < 64; ++f) {
    float mt = Mg[f * 68 + tx];
    const float4* wo4 = (const float4*)&poolF[f * 64 + e0];
#pragma unroll
    for (int q = 0; q < 4; ++q) {
      float4 w4 = wo4[q];
      macc[4 * q]     += mt * w4.x; macc[4 * q + 1] += mt * w4.y;
      macc[4 * q + 2] += mt * w4.z; macc[4 * q + 3] += mt * w4.w;
    }
  }
  __syncthreads();
  // GT2[o][d] = G[d][o]
#pragma unroll
  for (int e = 0; e < 16; ++e) Mg[(e0 + e) * 68 + tx] = macc[e];
  __syncthreads();

  // ---- Phase B: per distinct x pair -> output row; chunked scatter ----
  for (int i0 = 0; i0 < Px; i0 += 64) {
    int cN = min(64, Px - i0);
    for (int jj = ty; jj < cN; jj += 4) {
      int key = xkey[i0 + jj];
      int ia = key & 1023, ib = key >> 10;
      float fv = tabL[ia * 64 + tx] + tabL[ib * 64 + tx];
      fbF[ty * 64 + tx] = fv;
      float qr = 0.f;
      const float4* fb4 = (const float4*)&fbF[ty * 64];
#pragma unroll
      for (int q = 0; q < 16; ++q) {
        float4 f4v = fb4[q];
        qr += f4v.x * wa[4 * q] + f4v.y * wa[4 * q + 1] + f4v.z * wa[4 * q + 2] + f4v.w * wa[4 * q + 3];
      }
      float p = __expf(qr);
      float sum = p;
#pragma unroll
      for (int off = 32; off >= 1; off >>= 1) sum += __shfl_xor(sum, off, 64);
      float qh = p / sum * 0.125f;   // softmax * F^-0.5
      fbF[256 + ty * 64 + tx] = qh;
      float at = 0.f;
      const float4* qb4 = (const float4*)&fbF[256 + ty * 64];
      const float4* gt4 = (const float4*)&Mg[tx * 68];
#pragma unroll
      for (int q = 0; q < 16; ++q) {
        float4 qv = qb4[q];
        float4 gv = gt4[q];
        at += qv.x * gv.x + qv.y * gv.y + qv.z * gv.z + qv.w * gv.w;
      }
      float r = fv + at + bov;
      float mu = r;
#pragma unroll
      for (int off = 32; off >= 1; off >>= 1) mu += __shfl_xor(mu, off, 64);
      mu *= (1.f / 64.f);
      float dv = r - mu;
      float var = dv * dv;
#pragma unroll
      for (int off = 32; off >= 1; off >>= 1) var += __shfl_xor(var, off, 64);
      var *= (1.f / 64.f);
      poolF[jj * 64 + tx] = dv * rsqrtf(var + 1e-5f) * lg + lb;
    }
    __syncthreads();
    const nfloat4* w4 = (const nfloat4*)poolF;
    nfloat4* out4 = (nfloat4*)(out + (size_t)(dir * BB + b) * (LL * 64));
    for (int idx = tid; idx < 512 * 16; idx += 256) {
      int l = idx >> 4, q = idx & 15;
      int pid = pidxl[l];
      if (pid >= i0 && pid < i0 + cN)
        __builtin_nontemporal_store(w4[(pid - i0) * 16 + q], &out4[l * 16 + q]);
    }
    __syncthreads();
  }
}

extern "C" void kernel_launch(void* const* d_in, const int* in_sizes, int n_in,
                              void* d_out, int out_size, void* d_ws, size_t ws_size,
                              hipStream_t stream) {
  const int* src  = (const int*)d_in[0];
  const int* dst  = (const int*)d_in[1];
  const float* w1 = (const float*)d_in[2];
  const float* b1 = (const float*)d_in[3];
  const float* w2 = (const float*)d_in[4];
  const float* b2 = (const float*)d_in[5];
  const float* Wq = (const float*)d_in[6];
  const float* Wk = (const float*)d_in[7];
  const float* Wv = (const float*)d_in[8];
  const float* Wo = (const float*)d_in[9];
  const float* bo = (const float*)d_in[10];
  const float* lng = (const float*)d_in[11];
  const float* lnb = (const float*)d_in[12];
  float* out = (float*)d_out;

  k_all<<<dim3(512), dim3(256), 0, stream>>>(src, dst, w1, b1, w2, b2,
                                             Wq, Wk, Wv, Wo, bo, lng, lnb, out);
}

// Round 6
// 119.937 us; speedup vs baseline: 1.0824x; 1.0066x over previous
//
#include <hip/hip_runtime.h>
#include <hip/hip_bf16.h>

#define BB 256
#define LL 512

typedef float nfloat4 __attribute__((ext_vector_type(4)));

// ---------------------------------------------------------------------------
// Single fused kernel per (batch, dir):
//   histograms -> merged pair dedup (1 hash pass, side-tagged keys) ->
//   per-block encode table (distinct count values only; provably <= 63 rows)
//   -> linear cross-attn on deduped rows -> LN -> scatter to 512 positions.
// ~17 barriers/block (was ~25). Wk+Wv columns co-resident in VGPRs (budget
// 256 @ 2 blocks/CU). LDS ~64 KB -> 2 blocks/CU; grid 512 fully co-resident.
// ---------------------------------------------------------------------------
__global__ __launch_bounds__(256, 2) void k_all(
    const int* __restrict__ src, const int* __restrict__ dst,
    const float* __restrict__ w1, const float* __restrict__ b1,
    const float* __restrict__ w2, const float* __restrict__ b2,
    const float* __restrict__ Wq, const float* __restrict__ Wk,
    const float* __restrict__ Wv, const float* __restrict__ Wo,
    const float* __restrict__ bo, const float* __restrict__ lng,
    const float* __restrict__ lnb, float* __restrict__ out) {
  // ---- LDS layout (byte offsets; regions reused across phases) ----
  // [0,16384)      hist(4000 int) -> Phase A pA/vA (2x32x64 f) -> Wo stage ->
  //                Phase B row-out chunk (64x64 f)
  // [16384,32768)  hkey(1024)+hmult(1024) -> tabL 64x64 f
  // [32768,50176)  Mg: MT then GT2 (64 x stride-68 f)
  // [50176,58368)  xkey | ckey | cmult | pidxl (512 ints each)
  // [58368,60680)  cflag(513) + clist(64)
  // [60688,63760)  fbF: featb | qbuf | sred (256 f each)
  // [63760,63772)  npp[3]
  __shared__ __align__(16) char smem[63776];
  int*   hist  = (int*)smem;
  float* poolF = (float*)smem;
  int*   hkey  = (int*)(smem + 16384);
  int*   hmult = (int*)(smem + 20480);
  float* tabL  = (float*)(smem + 16384);   // 64 rows x 64
  float* Mg    = (float*)(smem + 32768);   // stride 68
  int*   xkey  = (int*)(smem + 50176);
  int*   ckey  = (int*)(smem + 52224);
  int*   cmult = (int*)(smem + 54272);
  int*   pidxl = (int*)(smem + 56320);
  int*   cflag = (int*)(smem + 58368);     // 513 ints -> becomes cmap
  int*   clist = (int*)(smem + 60424);     // 64 ints
  float* fbF   = (float*)(smem + 60688);   // featb 0..255|qbuf 256..511|sred 512..767
  int*   npp   = (int*)(smem + 63760);     // [0]=Pc [1]=Px [2]=nc

  int bd = blockIdx.x, b = bd >> 1, dir = bd & 1;
  int tid = threadIdx.x, tx = tid & 63, ty = tid >> 6;
  int e0 = ty * 16;

  // ---- phase 0: zero hist + hash + flags + counters (one barrier) ----
  const int* s = src + b * LL;
  const int* d = dst + b * LL;
  int sid0 = s[tid], sid1 = s[tid + 256];
  int did0 = d[tid], did1 = d[tid + 256];
  for (int i = tid; i < 4000; i += 256) hist[i] = 0;
  for (int i = tid; i < 1024; i += 256) { hkey[i] = -1; hmult[i] = 0; }
  for (int i = tid; i < 513; i += 256) cflag[i] = 0;
  if (tid < 3) npp[tid] = 0;
  __syncthreads();

  // ---- histograms (both sides) ----
  atomicAdd(&hist[sid0], 1);        atomicAdd(&hist[sid1], 1);
  atomicAdd(&hist[2000 + did0], 1); atomicAdd(&hist[2000 + did1], 1);
  __syncthreads();

  int x0 = dir ? did0 : sid0, x1 = dir ? did1 : sid1;
  int c0 = dir ? sid0 : did0, c1 = dir ? sid1 : did1;
  const int* hx = dir ? hist + 2000 : hist;
  const int* hc = dir ? hist : hist + 2000;

  // ---- merged dedup insert: 2 c-side + 2 x-side keys per thread ----
  int slot0 = 0, slot1 = 0;
#pragma unroll
  for (int r = 0; r < 4; ++r) {
    int side = r >> 1;   // 0 = context side, 1 = x side
    int id = (r == 0) ? c0 : (r == 1) ? c1 : (r == 2) ? x0 : x1;
    int ca = 0, cb = 0;
    if (id != 0) {
      if (side == 0) { ca = hc[id]; cb = hx[id]; }
      else           { ca = hx[id]; cb = hc[id]; }
    }
    int key = ca | (cb << 10) | (side << 20);
    int h = (int)(((unsigned)key * 2654435761u) >> 22) & 1023;
    while (true) {
      int old = atomicCAS(&hkey[h], -1, key);
      if (old == -1 || old == key) break;
      h = (h + 1) & 1023;
    }
    if (side == 0) atomicAdd(&hmult[h], 1);
    else if (r == 2) slot0 = h;
    else slot1 = h;
  }
  __syncthreads();

  // ---- compaction: one scan serves both sides ----
  for (int i = tid; i < 1024; i += 256) {
    int k = hkey[i];
    if (k != -1) {
      if (k & (1 << 20)) {
        int idx = atomicAdd(&npp[1], 1);
        xkey[idx] = k & 0xFFFFF;
        hkey[i] = idx;            // slot -> compacted x index
      } else {
        int idx = atomicAdd(&npp[0], 1);
        ckey[idx]  = k;
        cmult[idx] = hmult[i];
      }
    }
  }
  __syncthreads();
  int Pc = npp[0], Px = npp[1];
  pidxl[tid]       = hkey[slot0];
  pidxl[tid + 256] = hkey[slot1];
  // mark distinct count values (components of all keys)
  for (int i = tid; i < Pc; i += 256) { int k = ckey[i]; cflag[k & 1023] = 1; cflag[k >> 10] = 1; }
  for (int i = tid; i < Px; i += 256) { int k = xkey[i]; cflag[k & 1023] = 1; cflag[k >> 10] = 1; }
  __syncthreads();
  for (int c = tid; c < 513; c += 256) {
    if (cflag[c]) {
      int idx = atomicAdd(&npp[2], 1);   // provably <= 63 (31+31+zero)
      clist[idx] = c;
      cflag[c] = idx;                    // cflag becomes cmap
    }
  }
  __syncthreads();
  int nc = npp[2];
  // rewrite keys to table indices; build encode table rows concurrently
  for (int i = tid; i < Pc; i += 256) { int k = ckey[i]; ckey[i] = cflag[k & 1023] | (cflag[k >> 10] << 10); }
  for (int i = tid; i < Px; i += 256) { int k = xkey[i]; xkey[i] = cflag[k & 1023] | (cflag[k >> 10] << 10); }

  // ---- per-block encode table rows in LDS (hash region now dead) ----
  // T(c)[g] = b2[g] + sum_f relu(c*w1[f]+b1[f]) * w2[f][g]
  float wcA[64], wcB[64];
#pragma unroll
  for (int f = 0; f < 64; ++f) wcA[f] = w2[f * 64 + tx];   // w2 column tx
  {
    float w1v = w1[tx], b1v = b1[tx], b2v = b2[tx];
    for (int i = ty; i < nc; i += 4) {
      float c = (float)clist[i];
      fbF[ty * 64 + tx] = fmaxf(c * w1v + b1v, 0.f);       // wave-local h row
      float acc = b2v;
      const float4* h4 = (const float4*)&fbF[ty * 64];
#pragma unroll
      for (int q = 0; q < 16; ++q) {
        float4 hv = h4[q];
        acc += hv.x * wcA[4 * q] + hv.y * wcA[4 * q + 1] + hv.z * wcA[4 * q + 2] + hv.w * wcA[4 * q + 3];
      }
      tabL[i * 64 + tx] = acc;
    }
  }
  // load Wk / Wv columns while table settles
#pragma unroll
  for (int f = 0; f < 64; ++f) { wcA[f] = Wk[f * 64 + tx]; wcB[f] = Wv[f * 64 + tx]; }
  float macc[16];
#pragma unroll
  for (int e = 0; e < 16; ++e) macc[e] = 0.f;
  float sacc = 0.f;
  __syncthreads();   // tabL + rewritten keys ready; hist region dead -> pool

  // ---- Phase A: M[d][e] = sum_j n_j exp(k_j[d]) v_j[e] / colsum ----
  float* pA = poolF;          // 32 x 64
  float* vA = poolF + 2048;   // 32 x 64
  for (int j0 = 0; j0 < Pc; j0 += 32) {
    int cN = min(32, Pc - j0);
    for (int j = ty; j < cN; j += 4) {
      int key = ckey[j0 + j];
      int ia = key & 1023, ib = key >> 10;
      fbF[ty * 64 + tx] = tabL[ia * 64 + tx] + tabL[ib * 64 + tx];  // wave-local
      float kr = 0.f, vr = 0.f;
      const float4* fb4 = (const float4*)&fbF[ty * 64];
#pragma unroll
      for (int q = 0; q < 16; ++q) {
        float4 fv = fb4[q];
        kr += fv.x * wcA[4 * q] + fv.y * wcA[4 * q + 1] + fv.z * wcA[4 * q + 2] + fv.w * wcA[4 * q + 3];
        vr += fv.x * wcB[4 * q] + fv.y * wcB[4 * q + 1] + fv.z * wcB[4 * q + 2] + fv.w * wcB[4 * q + 3];
      }
      float p = __expf(kr) * (float)cmult[j0 + j];  // |kr| ~ O(10): safe fp32
      sacc += p;
      pA[j * 64 + tx] = p;
      vA[j * 64 + tx] = vr;
    }
    __syncthreads();
    // thread (tx,ty) owns M[d=tx][e0..e0+15]
    for (int jj = 0; jj < cN; ++jj) {
      float pg = pA[jj * 64 + tx];
      const float4* vb4 = (const float4*)&vA[jj * 64 + e0];
#pragma unroll
      for (int q = 0; q < 4; ++q) {
        float4 vv = vb4[q];
        macc[4 * q]     += pg * vv.x; macc[4 * q + 1] += pg * vv.y;
        macc[4 * q + 2] += pg * vv.z; macc[4 * q + 3] += pg * vv.w;
      }
    }
    __syncthreads();
  }
  fbF[512 + ty * 64 + tx] = sacc;
  __syncthreads();
  float inv = 1.f / (fbF[512 + tx] + fbF[576 + tx] + fbF[640 + tx] + fbF[704 + tx]);
  // MT[f][d] = M[d][f]
#pragma unroll
  for (int e = 0; e < 16; ++e) Mg[(e0 + e) * 68 + tx] = macc[e] * inv;
  for (int i = tid; i < 4096; i += 256) poolF[i] = Wo[i];  // stage Wo
#pragma unroll
  for (int f = 0; f < 64; ++f) wcA[f] = Wq[f * 64 + tx];   // Wq col (wcB dead)
  float bov = bo[tx], lg = lng[tx], lb = lnb[tx];
  __syncthreads();

  // ---- G = M @ Wo: thread owns G[d=tx][o=e0..e0+15] ----
#pragma unroll
  for (int e = 0; e < 16; ++e) macc[e] = 0.f;
  for (int f = 0; f < 64; ++f) {
    float mt = Mg[f * 68 + tx];
    const float4* wo4 = (const float4*)&poolF[f * 64 + e0];
#pragma unroll
    for (int q = 0; q < 4; ++q) {
      float4 w4 = wo4[q];
      macc[4 * q]     += mt * w4.x; macc[4 * q + 1] += mt * w4.y;
      macc[4 * q + 2] += mt * w4.z; macc[4 * q + 3] += mt * w4.w;
    }
  }
  __syncthreads();
  // GT2[o][d] = G[d][o]
#pragma unroll
  for (int e = 0; e < 16; ++e) Mg[(e0 + e) * 68 + tx] = macc[e];
  __syncthreads();

  // ---- Phase B: per distinct x pair -> output row; chunked scatter ----
  for (int i0 = 0; i0 < Px; i0 += 64) {
    int cN = min(64, Px - i0);
    for (int jj = ty; jj < cN; jj += 4) {
      int key = xkey[i0 + jj];
      int ia = key & 1023, ib = key >> 10;
      float fv = tabL[ia * 64 + tx] + tabL[ib * 64 + tx];
      fbF[ty * 64 + tx] = fv;
      float qr = 0.f;
      const float4* fb4 = (const float4*)&fbF[ty * 64];
#pragma unroll
      for (int q = 0; q < 16; ++q) {
        float4 f4v = fb4[q];
        qr += f4v.x * wcA[4 * q] + f4v.y * wcA[4 * q + 1] + f4v.z * wcA[4 * q + 2] + f4v.w * wcA[4 * q + 3];
      }
      float p = __expf(qr);
      float sum = p;
#pragma unroll
      for (int off = 32; off >= 1; off >>= 1) sum += __shfl_xor(sum, off, 64);
      float qh = p / sum * 0.125f;   // softmax * F^-0.5
      fbF[256 + ty * 64 + tx] = qh;
      float at = 0.f;
      const float4* qb4 = (const float4*)&fbF[256 + ty * 64];
      const float4* gt4 = (const float4*)&Mg[tx * 68];
#pragma unroll
      for (int q = 0; q < 16; ++q) {
        float4 qv = qb4[q];
        float4 gv = gt4[q];
        at += qv.x * gv.x + qv.y * gv.y + qv.z * gv.z + qv.w * gv.w;
      }
      float r = fv + at + bov;
      float mu = r;
#pragma unroll
      for (int off = 32; off >= 1; off >>= 1) mu += __shfl_xor(mu, off, 64);
      mu *= (1.f / 64.f);
      float dv = r - mu;
      float var = dv * dv;
#pragma unroll
      for (int off = 32; off >= 1; off >>= 1) var += __shfl_xor(var, off, 64);
      var *= (1.f / 64.f);
      poolF[jj * 64 + tx] = dv * rsqrtf(var + 1e-5f) * lg + lb;
    }
    __syncthreads();
    const nfloat4* w4 = (const nfloat4*)poolF;
    nfloat4* out4 = (nfloat4*)(out + (size_t)(dir * BB + b) * (LL * 64));
    for (int idx = tid; idx < 512 * 16; idx += 256) {
      int l = idx >> 4, q = idx & 15;
      int pid = pidxl[l];
      if (pid >= i0 && pid < i0 + cN)
        __builtin_nontemporal_store(w4[(pid - i0) * 16 + q], &out4[l * 16 + q]);
    }
    __syncthreads();
  }
}

extern "C" void kernel_launch(void* const* d_in, const int* in_sizes, int n_in,
                              void* d_out, int out_size, void* d_ws, size_t ws_size,
                              hipStream_t stream) {
  const int* src  = (const int*)d_in[0];
  const int* dst  = (const int*)d_in[1];
  const float* w1 = (const float*)d_in[2];
  const float* b1 = (const float*)d_in[3];
  const float* w2 = (const float*)d_in[4];
  const float* b2 = (const float*)d_in[5];
  const float* Wq = (const float*)d_in[6];
  const float* Wk = (const float*)d_in[7];
  const float* Wv = (const float*)d_in[8];
  const float* Wo = (const float*)d_in[9];
  const float* bo = (const float*)d_in[10];
  const float* lng = (const float*)d_in[11];
  const float* lnb = (const float*)d_in[12];
  float* out = (float*)d_out;

  k_all<<<dim3(512), dim3(256), 0, stream>>>(src, dst, w1, b1, w2, b2,
                                             Wq, Wk, Wv, Wo, bo, lng, lnb, out);
}